// Round 7
// baseline (223.218 us; speedup 1.0000x reference)
//
#include <hip/hip_runtime.h>
#include <cstdint>

#define BATCH 8
#define LQ 512
#define LK 2048
#define NH 16
#define DIM 64
#define HID 1024
#define NTOK (BATCH * LQ)   // 4096 tokens
#define NKT (LK / 64)       // 32 key tiles
#define KP 72               // pad: 144B row stride, 16B-aligned (R5 lesson: pad % 8 == 0!)
#define SC 0.1803368801111204f    // 0.125 * log2(e): folded into Q at pack time
#define NEGM (-1.4426950408889634e8f)  // -1e8 * log2(e): key-mask in exp2 domain

typedef _Float16 f16x8 __attribute__((ext_vector_type(8)));
typedef __fp16 half2v __attribute__((ext_vector_type(2)));
typedef float f32x4 __attribute__((ext_vector_type(4)));

#define MFMA(a, b, c) __builtin_amdgcn_mfma_f32_16x16x32_f16((a), (b), (c), 0, 0, 0)

__device__ __forceinline__ f16x8 ld8(const _Float16* p) { return *(const f16x8*)p; }

// async global->LDS, 16B per lane; lds dst is wave-uniform base (HW adds lane*16)
__device__ __forceinline__ void gl_lds16(const void* g, void* l) {
  __builtin_amdgcn_global_load_lds(
      (const __attribute__((address_space(1))) uint32_t*)g,
      (__attribute__((address_space(3))) uint32_t*)l, 16, 0, 0);
}

// LDS flush + barrier that does NOT drain vmcnt: in-flight global->VGPR
// loads survive (HK/m194 idiom).
__device__ __forceinline__ void lds_barrier() {
  asm volatile("s_waitcnt lgkmcnt(0)" ::: "memory");
  __builtin_amdgcn_s_barrier();
}

// 8 consecutive fp32 -> fp16 fragment (RTE scalar casts)
__device__ __forceinline__ f16x8 cvt8(const float* p) {
  const float4 a = *(const float4*)p;
  const float4 b = *(const float4*)(p + 4);
  f16x8 v;
  v[0] = (_Float16)a.x; v[1] = (_Float16)a.y; v[2] = (_Float16)a.z; v[3] = (_Float16)a.w;
  v[4] = (_Float16)b.x; v[5] = (_Float16)b.y; v[6] = (_Float16)b.z; v[7] = (_Float16)b.w;
  return v;
}

// pack 4 fp32 -> 4 fp16 (2x v_cvt_pkrtz) for ds_write_b64
__device__ __forceinline__ uint2 pk4(float a, float b, float c, float d) {
  union { half2v h2[2]; uint2 u; } t;
  t.h2[0] = __builtin_amdgcn_cvt_pkrtz(a, b);
  t.h2[1] = __builtin_amdgcn_cvt_pkrtz(c, d);
  return t.u;
}

// pack 2 fp32 -> dword of 2 fp16
__device__ __forceinline__ uint32_t pk2(float a, float b) {
  union { half2v h2; uint32_t u; } t;
  t.h2 = __builtin_amdgcn_cvt_pkrtz(a, b);
  return t.u;
}

// two float4 -> f16x8 via pkrtz
__device__ __forceinline__ f16x8 pk8(float4 a, float4 b) {
  union { half2v h2[4]; f16x8 v; } t;
  t.h2[0] = __builtin_amdgcn_cvt_pkrtz(a.x, a.y);
  t.h2[1] = __builtin_amdgcn_cvt_pkrtz(a.z, a.w);
  t.h2[2] = __builtin_amdgcn_cvt_pkrtz(b.x, b.y);
  t.h2[3] = __builtin_amdgcn_cvt_pkrtz(b.z, b.w);
  return t.v;
}

// ---------------------------------------------------------------------------
// Fully fused attention: Q/K/V projections + flash attention in one kernel.
// ROUND 7 = R2 STRUCTURE (best base, 79.2us) + SHUFFLE-BASED P TRANSPOSE.
// Session evidence: attn is pinned at ~80us across 1-2 waves/SIMD, single/
// double KV buffering, pad variants -> NOT TLP-bound, NOT conflict-bound;
// the per-tile serial chain is the wall. The one untouched serial link is
// the P C-layout -> A-layout LDS round trip (write 8x b64 -> lgkm drain ->
// read 4x b128, ~300-400cy + conflicts, EVERY tile). Replaced with pure
// in-register redistribution: lane (quad,l16) needs keys quad*8+j; with
// PK[nt][h] = pkrtz(p[nt][2h],p[nt][2h+1]) the B-frag is {PK[sel][0..1] of
// lane s0, same of lane s1}, s0 = ((2*quad)&3)*16+l16, s1 = s0+16,
// sel = quad>>1 (ap0: nt0/1, ap1: nt2/3). 16 bpermutes + 8 selects per qt,
// all-lane uniform (both shuffles executed, select after). Same pkrtz pairs
// -> bit-identical numerics. Removes 64KB/tile LDS + one lgkm stall.
// Per (b,h) x 256-q block: grid (128,2), 512 thr / 8 waves. Wave-specialized
// projections (waves 0-3: K, 4-7: V), reg-staged X, double-buffered Kl/Vl,
// ONE lgkm-only barrier per tile, setprio on MFMA clusters, KP=72.
// ---------------------------------------------------------------------------
__global__ __launch_bounds__(512, 2) void attn_kernel(
    const float* __restrict__ Xq, const float* __restrict__ Xk,
    const float* __restrict__ Wq, const float* __restrict__ Wk,
    const float* __restrict__ Wv, const float* __restrict__ kg_mask,
    _Float16* __restrict__ ctx) {
  __shared__ __align__(16) _Float16 Kl[2][64 * KP];    // 18 KB: [key][e]
  __shared__ __align__(16) _Float16 Vl[2][64 * KP];    // 18 KB: [d][key]
  __shared__ __align__(16) _Float16 Pl[8][2][16 * KP]; // 36 KB: Q transpose (prologue only)
  __shared__ __align__(16) float    Ml[LK];            // 8 KB:  (1-mask)*NEGM
  const int tid = threadIdx.x;
  const int wave = tid >> 6, lane = tid & 63, l16 = lane & 15, quad = lane >> 4;
  const int kw = wave & 3;  // row-group for X/K/V projection work
  const int b = blockIdx.x >> 4, h = blockIdx.x & 15;
  const int qbase = blockIdx.y * 256;
  const float* Xg = Xk + (size_t)b * LK * HID + h * 64;  // key-side X, this head's cols
  const float* mg = kg_mask + (size_t)b * LK;

  // X register staging: lane (quad,l16) of wave kw holds row kw*16+l16,
  // logical chunks 2q,2q+1 (floats 8q..8q+7) and 2q+8,2q+9 (8q+32..8q+39).
  const float* xrow0 = Xg + (size_t)(kw * 16 + l16) * HID + quad * 8;
  float4 xf0, xf1, xf2, xf3;
  auto loadX = [&](int kt) {
    const float* xr = xrow0 + (size_t)kt * HID;
    xf0 = *(const float4*)(xr);
    xf1 = *(const float4*)(xr + 4);
    xf2 = *(const float4*)(xr + 32);
    xf3 = *(const float4*)(xr + 36);
  };
  loadX(0);  // in flight across the whole prologue

  // mask pre-scale into LDS: 512 threads x float4 covers LK=2048 exactly.
  {
    const float4 m4 = *(const float4*)(mg + tid * 4);
    float4 mo;
    mo.x = (1.f - m4.x) * NEGM;
    mo.y = (1.f - m4.y) * NEGM;
    mo.z = (1.f - m4.z) * NEGM;
    mo.w = (1.f - m4.w) * NEGM;
    *(float4*)(Ml + tid * 4) = mo;
  }

  // ---- fused Q projection: D[d_out][q] = Wq . Xq^T, scaled by SC ----
  f16x8 aq0[2], aq1[2];
  {
    f16x8 wq0[4], wq1[4];
#pragma unroll
    for (int nt = 0; nt < 4; ++nt) {
      const float* wp = Wq + (nt * 16 + l16) * DIM + quad * 8;
      wq0[nt] = cvt8(wp);
      wq1[nt] = cvt8(wp + 32);
    }
#pragma unroll
    for (int qt = 0; qt < 2; ++qt) {
      const int qg = qbase + wave * 32 + qt * 16 + l16;
      const float* xpq = Xq + (size_t)(b * LQ + qg) * HID + h * 64 + quad * 8;
      const f16x8 bq0 = cvt8(xpq), bq1 = cvt8(xpq + 32);
#pragma unroll
      for (int nt = 0; nt < 4; ++nt) {
        f32x4 d = {0.f, 0.f, 0.f, 0.f};
        d = MFMA(wq0[nt], bq0, d);
        d = MFMA(wq1[nt], bq1, d);
        *(uint2*)&Pl[wave][qt][l16 * KP + nt * 16 + quad * 4] =
            pk4(d[0] * SC, d[1] * SC, d[2] * SC, d[3] * SC);
      }
      aq0[qt] = ld8(&Pl[wave][qt][l16 * KP + quad * 8]);
      aq1[qt] = ld8(&Pl[wave][qt][l16 * KP + 32 + quad * 8]);
    }
  }

  // ---- projection weight fragments, once per block: waves 0-3 hold Wk
  // (A-operand of K proj), waves 4-7 hold Wv (B-operand of V proj). ----
  const float* Wsel = (wave < 4) ? Wk : Wv;
  f16x8 aw0[4], aw1[4];
#pragma unroll
  for (int nt = 0; nt < 4; ++nt) {
    const float* wp = Wsel + (nt * 16 + l16) * DIM + quad * 8;
    aw0[nt] = cvt8(wp);
    aw1[nt] = cvt8(wp + 32);
  }

  const f32x4 z4 = {0.f, 0.f, 0.f, 0.f};

  // ---- proj(0) into buffer 0 (xf holds X[0]; compiler waits vmcnt here) ----
  {
    const f16x8 bx0 = pk8(xf0, xf1), bx1 = pk8(xf2, xf3);
    if (wave < 4) {
#pragma unroll
      for (int nt = 0; nt < 4; ++nt) {
        f32x4 d = z4;
        d = MFMA(aw0[nt], bx0, d);
        d = MFMA(aw1[nt], bx1, d);
        *(uint2*)&Kl[0][(kw * 16 + l16) * KP + nt * 16 + quad * 4] =
            pk4(d[0], d[1], d[2], d[3]);
      }
    } else {
#pragma unroll
      for (int dt = 0; dt < 4; ++dt) {
        f32x4 d = z4;
        d = MFMA(bx0, aw0[dt], d);
        d = MFMA(bx1, aw1[dt], d);
        *(uint2*)&Vl[0][(dt * 16 + l16) * KP + kw * 16 + quad * 4] =
            pk4(d[0], d[1], d[2], d[3]);
      }
    }
  }
  loadX(64);      // X[1] in flight across the barrier
  lds_barrier();  // publishes Ml + KV[0]; X loads NOT drained

  f32x4 o[2][4];
  float l_run[2] = {0.f, 0.f};
#pragma unroll
  for (int qt = 0; qt < 2; ++qt)
#pragma unroll
    for (int i = 0; i < 4; ++i) o[qt][i] = z4;

  // shuffle sources for the P redistribution (constant per lane)
  const int s0 = (((2 * quad) & 3) << 4) | l16;
  const int s1 = s0 + 16;
  const bool qlo = quad < 2;

  for (int t = 0; t < NKT; ++t) {
    const int buf = t & 1;
    const int kt = t * 64;

    // ---- proj(t+1) into buf^1 (reads nothing of buf; races nothing) ----
    if (t + 1 < NKT) {
      const f16x8 bx0 = pk8(xf0, xf1), bx1 = pk8(xf2, xf3);  // counted vmcnt wait
      if (wave < 4) {
#pragma unroll
        for (int nt = 0; nt < 4; ++nt) {
          f32x4 d = z4;
          d = MFMA(aw0[nt], bx0, d);
          d = MFMA(aw1[nt], bx1, d);
          *(uint2*)&Kl[buf ^ 1][(kw * 16 + l16) * KP + nt * 16 + quad * 4] =
              pk4(d[0], d[1], d[2], d[3]);
        }
      } else {
#pragma unroll
        for (int dt = 0; dt < 4; ++dt) {
          f32x4 d = z4;
          d = MFMA(bx0, aw0[dt], d);
          d = MFMA(bx1, aw1[dt], d);
          *(uint2*)&Vl[buf ^ 1][(dt * 16 + l16) * KP + kw * 16 + quad * 4] =
              pk4(d[0], d[1], d[2], d[3]);
        }
      }
      if (t + 2 < NKT) loadX(kt + 128);  // X[t+2]: in flight across next barrier
    }

    // mask from LDS (pre-scaled); quad lanes broadcast the same float4
    float4 mv[4];
#pragma unroll
    for (int nt = 0; nt < 4; ++nt)
      mv[nt] = *(const float4*)(Ml + kt + nt * 16 + quad * 4);

    // S^T = K.Q^T : D[key=nt*16+quad*4+r][q=l16]; P = exp2(S + mask)
    float p[2][4][4];
    __builtin_amdgcn_s_setprio(1);
#pragma unroll
    for (int nt = 0; nt < 4; ++nt) {
      const f16x8 kb0 = ld8(&Kl[buf][(nt * 16 + l16) * KP + quad * 8]);
      const f16x8 kb1 = ld8(&Kl[buf][(nt * 16 + l16) * KP + 32 + quad * 8]);
#pragma unroll
      for (int qt = 0; qt < 2; ++qt) {
        f32x4 s = z4;
        s = MFMA(kb0, aq0[qt], s);
        s = MFMA(kb1, aq1[qt], s);
        const float e0 = __builtin_amdgcn_exp2f(s[0] + mv[nt].x);
        const float e1 = __builtin_amdgcn_exp2f(s[1] + mv[nt].y);
        const float e2 = __builtin_amdgcn_exp2f(s[2] + mv[nt].z);
        const float e3 = __builtin_amdgcn_exp2f(s[3] + mv[nt].w);
        l_run[qt] += (e0 + e1) + (e2 + e3);
        p[qt][nt][0] = e0; p[qt][nt][1] = e1; p[qt][nt][2] = e2; p[qt][nt][3] = e3;
      }
    }
    __builtin_amdgcn_s_setprio(0);

    // P: C-layout -> A-layout fully in-register (no LDS round trip).
    // PK[nt][h] = pk(p[nt][2h], p[nt][2h+1]); target lane (quad,l16) needs
    // keys quad*8+j = {PK[sel][0..1] of lane s0, PK[sel][0..1] of lane s1},
    // sel = quad>>1 (ap0: nt 0/1; ap1: nt 2/3). Both shuffles execute for
    // all lanes (no predicated shfl), select after.
    f16x8 ap0[2], ap1[2];
#pragma unroll
    for (int qt = 0; qt < 2; ++qt) {
      uint32_t PK[4][2];
#pragma unroll
      for (int nt = 0; nt < 4; ++nt) {
        PK[nt][0] = pk2(p[qt][nt][0], p[qt][nt][1]);
        PK[nt][1] = pk2(p[qt][nt][2], p[qt][nt][3]);
      }
      // ap0: nt-pair (0,1)
      {
        const uint32_t a0 = (uint32_t)__shfl((int)PK[0][0], s0);
        const uint32_t b0 = (uint32_t)__shfl((int)PK[1][0], s0);
        const uint32_t a1 = (uint32_t)__shfl((int)PK[0][1], s0);
        const uint32_t b1 = (uint32_t)__shfl((int)PK[1][1], s0);
        const uint32_t a2 = (uint32_t)__shfl((int)PK[0][0], s1);
        const uint32_t b2 = (uint32_t)__shfl((int)PK[1][0], s1);
        const uint32_t a3 = (uint32_t)__shfl((int)PK[0][1], s1);
        const uint32_t b3 = (uint32_t)__shfl((int)PK[1][1], s1);
        union { uint32_t u[4]; f16x8 v; } t0;
        t0.u[0] = qlo ? a0 : b0;
        t0.u[1] = qlo ? a1 : b1;
        t0.u[2] = qlo ? a2 : b2;
        t0.u[3] = qlo ? a3 : b3;
        ap0[qt] = t0.v;
      }
      // ap1: nt-pair (2,3)
      {
        const uint32_t a0 = (uint32_t)__shfl((int)PK[2][0], s0);
        const uint32_t b0 = (uint32_t)__shfl((int)PK[3][0], s0);
        const uint32_t a1 = (uint32_t)__shfl((int)PK[2][1], s0);
        const uint32_t b1 = (uint32_t)__shfl((int)PK[3][1], s0);
        const uint32_t a2 = (uint32_t)__shfl((int)PK[2][0], s1);
        const uint32_t b2 = (uint32_t)__shfl((int)PK[3][0], s1);
        const uint32_t a3 = (uint32_t)__shfl((int)PK[2][1], s1);
        const uint32_t b3 = (uint32_t)__shfl((int)PK[3][1], s1);
        union { uint32_t u[4]; f16x8 v; } t1;
        t1.u[0] = qlo ? a0 : b0;
        t1.u[1] = qlo ? a1 : b1;
        t1.u[2] = qlo ? a2 : b2;
        t1.u[3] = qlo ? a3 : b3;
        ap1[qt] = t1.v;
      }
    }

    // O^T += V.P^T : D[d=dt*16+quad*4+r][q=l16]
    __builtin_amdgcn_s_setprio(1);
#pragma unroll
    for (int dt = 0; dt < 4; ++dt) {
      const f16x8 vb0 = ld8(&Vl[buf][(dt * 16 + l16) * KP + quad * 8]);
      const f16x8 vb1 = ld8(&Vl[buf][(dt * 16 + l16) * KP + 32 + quad * 8]);
#pragma unroll
      for (int qt = 0; qt < 2; ++qt) {
        o[qt][dt] = MFMA(vb0, ap0[qt], o[qt][dt]);
        o[qt][dt] = MFMA(vb1, ap1[qt], o[qt][dt]);
      }
    }
    __builtin_amdgcn_s_setprio(0);

    lds_barrier();  // publishes KV[t+1]; guards buf reuse; X loads survive
  }

  // row-sum: lane covers its quad's 16 keys; finish across quads
  float inv[2];
#pragma unroll
  for (int qt = 0; qt < 2; ++qt) {
    float s = l_run[qt];
    s += __shfl_xor(s, 16);
    s += __shfl_xor(s, 32);
    inv[qt] = 1.f / s;
  }
  // ctx (token, h*64+d): lane's 4 d-values contiguous -> packed 8B stores
#pragma unroll
  for (int qt = 0; qt < 2; ++qt) {
    const int qg = qbase + wave * 32 + qt * 16 + l16;
    _Float16* base = ctx + (size_t)(b * LQ + qg) * HID + h * 64;
#pragma unroll
    for (int dt = 0; dt < 4; ++dt)
      *(uint2*)(base + dt * 16 + quad * 4) =
          pk4(o[qt][dt][0] * inv[qt], o[qt][dt][1] * inv[qt],
              o[qt][dt][2] * inv[qt], o[qt][dt][3] * inv[qt]);
  }
}

// ---------------------------------------------------------------------------
// W_lin fp32 -> fp16 (once; 2MB result stays L2-resident for linear_kernel)
// ---------------------------------------------------------------------------
__global__ __launch_bounds__(256) void wconv_kernel(const float* __restrict__ W,
                                                    _Float16* __restrict__ Wh) {
  const int i = blockIdx.x * 256 + threadIdx.x;
  const float4 v = ((const float4*)W)[i];
  ((uint2*)Wh)[i] = pk4(v.x, v.y, v.z, v.w);
}

// ---------------------------------------------------------------------------
// lin = ctx @ Wh^T + b; X = erf-GELU(lin) + resid. 128x128 tile, 512 threads
// (8 waves as 2x4), BK=64, double-buffered global_load_lds, 1 barrier/chunk.
// ---------------------------------------------------------------------------
__global__ __launch_bounds__(512) void linear_kernel(const _Float16* __restrict__ A,
                                                     const _Float16* __restrict__ Wh,
                                                     const float* __restrict__ bias,
                                                     const float* __restrict__ resid,
                                                     float* __restrict__ Xout) {
  __shared__ __align__(16) _Float16 Al[2][128 * 64];
  __shared__ __align__(16) _Float16 Bl[2][128 * 64];
  const int tid = threadIdx.x;
  const int wave = tid >> 6, lane = tid & 63, l16 = lane & 15, quad = lane >> 4;
  const int wm = wave >> 2, wn = wave & 3;
  const int nbase = blockIdx.x * 128, mbase = blockIdx.y * 128;
  const int srow = wave * 16 + (lane >> 3);
  const int sc = lane & 7;

  auto stage = [&](int kk, int nbuf) {
#pragma unroll
    for (int i = 0; i < 2; ++i) {
      const int row = srow + i * 8;
      const int c = sc ^ (row & 7);
      gl_lds16(A + (size_t)(mbase + row) * HID + kk + c * 8,
               &Al[nbuf][(wave * 16 + i * 8) * 64]);
      gl_lds16(Wh + (size_t)(nbase + row) * HID + kk + c * 8,
               &Bl[nbuf][(wave * 16 + i * 8) * 64]);
    }
  };

  const f32x4 z4 = {0.f, 0.f, 0.f, 0.f};
  f32x4 acc[4][2];
#pragma unroll
  for (int mt = 0; mt < 4; ++mt)
#pragma unroll
    for (int nt = 0; nt < 2; ++nt) acc[mt][nt] = z4;

  stage(0, 0);
  for (int t = 0; t < HID / 64; ++t) {
    const int buf = t & 1;
    __syncthreads();
    if (t + 1 < HID / 64) stage((t + 1) * 64, buf ^ 1);
    const int sw = l16 & 7;
    f16x8 b0[2], b1[2];
#pragma unroll
    for (int nt = 0; nt < 2; ++nt) {
      const int brow = wn * 32 + nt * 16 + l16;
      b0[nt] = ld8(&Bl[buf][brow * 64 + (quad ^ sw) * 8]);
      b1[nt] = ld8(&Bl[buf][brow * 64 + ((quad + 4) ^ sw) * 8]);
    }
#pragma unroll
    for (int mt = 0; mt < 4; ++mt) {
      const int arow = wm * 64 + mt * 16 + l16;
      const f16x8 a0 = ld8(&Al[buf][arow * 64 + (quad ^ sw) * 8]);
      const f16x8 a1 = ld8(&Al[buf][arow * 64 + ((quad + 4) ^ sw) * 8]);
#pragma unroll
      for (int nt = 0; nt < 2; ++nt) {
        acc[mt][nt] = MFMA(a0, b0[nt], acc[mt][nt]);
        acc[mt][nt] = MFMA(a1, b1[nt], acc[mt][nt]);
      }
    }
  }
#pragma unroll
  for (int nt = 0; nt < 2; ++nt) {
    const int col = nbase + wn * 32 + nt * 16 + l16;
    const float bv = bias[col];
#pragma unroll
    for (int mt = 0; mt < 4; ++mt) {
#pragma unroll
      for (int r = 0; r < 4; ++r) {
        const int row = mbase + wm * 64 + mt * 16 + quad * 4 + r;
        const float v = acc[mt][nt][r] + bv;
        const float g = 0.5f * v * (1.f + erff(v * 0.70710678118654752f));
        Xout[(size_t)row * HID + col] = g + resid[(size_t)row * HID + col];
      }
    }
  }
}

// ---------------------------------------------------------------------------
// LayerNorm over HID=1024 per token row.
// ---------------------------------------------------------------------------
__global__ __launch_bounds__(256) void ln_kernel(const float* __restrict__ X,
                                                 const float* __restrict__ gamma,
                                                 const float* __restrict__ beta,
                                                 float* __restrict__ out) {
  const int row = blockIdx.x, tid = threadIdx.x;
  const int lane = tid & 63, wave = tid >> 6;
  const float4 v = *(const float4*)(X + (size_t)row * HID + tid * 4);
  float s1 = v.x + v.y + v.z + v.w;
  float s2 = v.x * v.x + v.y * v.y + v.z * v.z + v.w * v.w;
#pragma unroll
  for (int off = 1; off < 64; off <<= 1) {
    s1 += __shfl_xor(s1, off);
    s2 += __shfl_xor(s2, off);
  }
  __shared__ float r1[4], r2[4];
  if (lane == 0) { r1[wave] = s1; r2[wave] = s2; }
  __syncthreads();
  s1 = r1[0] + r1[1] + r1[2] + r1[3];
  s2 = r2[0] + r2[1] + r2[2] + r2[3];
  const float mu = s1 * (1.f / HID);
  const float var = s2 * (1.f / HID) - mu * mu;
  const float rstd = rsqrtf(var + 1e-5f);
  const float4 g = *(const float4*)(gamma + tid * 4);
  const float4 be = *(const float4*)(beta + tid * 4);
  float4 ov;
  ov.x = (v.x - mu) * rstd * g.x + be.x;
  ov.y = (v.y - mu) * rstd * g.y + be.y;
  ov.z = (v.z - mu) * rstd * g.z + be.z;
  ov.w = (v.w - mu) * rstd * g.w + be.w;
  *(float4*)(out + (size_t)row * HID + tid * 4) = ov;
}

// ---------------------------------------------------------------------------
// Workspace:
//   ctx fp16 [ 0, 8M)
//   Xb  fp32 [ 8M,24M)
//   Wh  fp16 [24M,26M)
// ---------------------------------------------------------------------------
extern "C" void kernel_launch(void* const* d_in, const int* in_sizes, int n_in,
                              void* d_out, int out_size, void* d_ws, size_t ws_size,
                              hipStream_t stream) {
  (void)in_sizes; (void)n_in; (void)out_size; (void)ws_size;
  const float* input_embed = (const float*)d_in[0];
  const float* kg_embed    = (const float*)d_in[1];
  // d_in[2] = input_mask: additive per-query constant -> softmax-invariant, unused
  const float* kg_mask = (const float*)d_in[3];
  const float* Wq    = (const float*)d_in[4];
  const float* Wk    = (const float*)d_in[5];
  const float* Wv    = (const float*)d_in[6];
  const float* W_lin = (const float*)d_in[7];
  const float* b_lin = (const float*)d_in[8];
  const float* gamma = (const float*)d_in[9];
  const float* beta  = (const float*)d_in[10];

  char* ws = (char*)d_ws;
  _Float16* ctx = (_Float16*)(ws);
  float*    Xb  = (float*)(ws + (8u << 20));
  _Float16* Wh  = (_Float16*)(ws + (24u << 20));

  attn_kernel<<<dim3(128, 2), dim3(512), 0, stream>>>(input_embed, kg_embed, Wq, Wk, Wv,
                                                      kg_mask, ctx);
  wconv_kernel<<<dim3(1024), dim3(256), 0, stream>>>(W_lin, Wh);
  linear_kernel<<<dim3(8, 32), dim3(512), 0, stream>>>(ctx, Wh, b_lin, input_embed, Xb);
  ln_kernel<<<dim3(NTOK), dim3(256), 0, stream>>>(Xb, gamma, beta, (float*)d_out);
}

// Round 8
// 210.651 us; speedup vs baseline: 1.0597x; 1.0597x over previous
//
#include <hip/hip_runtime.h>
#include <cstdint>

#define BATCH 8
#define LQ 512
#define LK 2048
#define NH 16
#define DIM 64
#define HID 1024
#define NTOK (BATCH * LQ)   // 4096 tokens
#define NKT (LK / 64)       // 32 key tiles
#define KP 72               // pad: 144B row stride, 16B-aligned (R5 lesson: pad % 8 == 0!)
#define SC 0.1803368801111204f    // 0.125 * log2(e): folded into Q at pack time
#define NEGM (-1.4426950408889634e8f)  // -1e8 * log2(e): key-mask in exp2 domain

typedef _Float16 f16x8 __attribute__((ext_vector_type(8)));
typedef __fp16 half2v __attribute__((ext_vector_type(2)));
typedef float f32x4 __attribute__((ext_vector_type(4)));

#define MFMA(a, b, c) __builtin_amdgcn_mfma_f32_16x16x32_f16((a), (b), (c), 0, 0, 0)

__device__ __forceinline__ f16x8 ld8(const _Float16* p) { return *(const f16x8*)p; }

// async global->LDS, 16B per lane; lds dst is wave-uniform base (HW adds lane*16)
__device__ __forceinline__ void gl_lds16(const void* g, void* l) {
  __builtin_amdgcn_global_load_lds(
      (const __attribute__((address_space(1))) uint32_t*)g,
      (__attribute__((address_space(3))) uint32_t*)l, 16, 0, 0);
}

// LDS flush + barrier that does NOT drain vmcnt: in-flight global->VGPR
// loads survive (HK/m194 idiom).
__device__ __forceinline__ void lds_barrier() {
  asm volatile("s_waitcnt lgkmcnt(0)" ::: "memory");
  __builtin_amdgcn_s_barrier();
}

// 8 consecutive fp32 -> fp16 fragment (RTE scalar casts)
__device__ __forceinline__ f16x8 cvt8(const float* p) {
  const float4 a = *(const float4*)p;
  const float4 b = *(const float4*)(p + 4);
  f16x8 v;
  v[0] = (_Float16)a.x; v[1] = (_Float16)a.y; v[2] = (_Float16)a.z; v[3] = (_Float16)a.w;
  v[4] = (_Float16)b.x; v[5] = (_Float16)b.y; v[6] = (_Float16)b.z; v[7] = (_Float16)b.w;
  return v;
}

// pack 4 fp32 -> 4 fp16 (2x v_cvt_pkrtz) for ds_write_b64
__device__ __forceinline__ uint2 pk4(float a, float b, float c, float d) {
  union { half2v h2[2]; uint2 u; } t;
  t.h2[0] = __builtin_amdgcn_cvt_pkrtz(a, b);
  t.h2[1] = __builtin_amdgcn_cvt_pkrtz(c, d);
  return t.u;
}

// two float4 -> f16x8 via pkrtz
__device__ __forceinline__ f16x8 pk8(float4 a, float4 b) {
  union { half2v h2[4]; f16x8 v; } t;
  t.h2[0] = __builtin_amdgcn_cvt_pkrtz(a.x, a.y);
  t.h2[1] = __builtin_amdgcn_cvt_pkrtz(a.z, a.w);
  t.h2[2] = __builtin_amdgcn_cvt_pkrtz(b.x, b.y);
  t.h2[3] = __builtin_amdgcn_cvt_pkrtz(b.z, b.w);
  return t.v;
}

// ---------------------------------------------------------------------------
// Fully fused attention: Q/K/V projections + flash attention in one kernel.
// ROUND 8 = R2 STRUCTURE (session best, 79.2us) + MASK VIA MFMA C-INIT.
// R7 lesson: __shfl = ds_bpermute = SAME LDS pipe -> shuffle transpose
// regressed; reverted to the LDS P round-trip. This round removes the mask
// path from the LDS pipe instead: the S accumulator is INITIALIZED to
// (1-mask)*NEGM (C-in of the first S-MFMA has exactly the D[key][q] layout
// the additive mask needs), with mask float4s loaded per-tile from global
// (L2-hot, idle vmem pipe, issued at tile top so the X-prefetch vmcnt FIFO
// order is preserved). Deletes: Ml (8KB LDS + init), 4 b128 LDS reads per
// wave per tile (~12% of LDS issue), 16 VALU adds per wave per tile.
// Per (b,h) x 256-q block: grid (128,2), 512 thr / 8 waves. Wave-specialized
// projections (waves 0-3: K, 4-7: V), reg-staged X, double-buffered Kl/Vl,
// ONE lgkm-only barrier per tile, setprio on MFMA clusters, KP=72.
// ---------------------------------------------------------------------------
__global__ __launch_bounds__(512, 2) void attn_kernel(
    const float* __restrict__ Xq, const float* __restrict__ Xk,
    const float* __restrict__ Wq, const float* __restrict__ Wk,
    const float* __restrict__ Wv, const float* __restrict__ kg_mask,
    _Float16* __restrict__ ctx) {
  __shared__ __align__(16) _Float16 Kl[2][64 * KP];    // 18 KB: [key][e]
  __shared__ __align__(16) _Float16 Vl[2][64 * KP];    // 18 KB: [d][key]
  __shared__ __align__(16) _Float16 Pl[8][2][16 * KP]; // 36 KB: per-wave/qt P transpose
  const int tid = threadIdx.x;
  const int wave = tid >> 6, lane = tid & 63, l16 = lane & 15, quad = lane >> 4;
  const int kw = wave & 3;  // row-group for X/K/V projection work
  const int b = blockIdx.x >> 4, h = blockIdx.x & 15;
  const int qbase = blockIdx.y * 256;
  const float* Xg = Xk + (size_t)b * LK * HID + h * 64;  // key-side X, this head's cols
  const float* mg = kg_mask + (size_t)b * LK;

  // X register staging: lane (quad,l16) of wave kw holds row kw*16+l16,
  // logical chunks 2q,2q+1 (floats 8q..8q+7) and 2q+8,2q+9 (8q+32..8q+39).
  const float* xrow0 = Xg + (size_t)(kw * 16 + l16) * HID + quad * 8;
  float4 xf0, xf1, xf2, xf3;
  auto loadX = [&](int kt) {
    const float* xr = xrow0 + (size_t)kt * HID;
    xf0 = *(const float4*)(xr);
    xf1 = *(const float4*)(xr + 4);
    xf2 = *(const float4*)(xr + 32);
    xf3 = *(const float4*)(xr + 36);
  };
  loadX(0);  // in flight across the whole prologue

  // ---- fused Q projection: D[d_out][q] = Wq . Xq^T, scaled by SC ----
  f16x8 aq0[2], aq1[2];
  {
    f16x8 wq0[4], wq1[4];
#pragma unroll
    for (int nt = 0; nt < 4; ++nt) {
      const float* wp = Wq + (nt * 16 + l16) * DIM + quad * 8;
      wq0[nt] = cvt8(wp);
      wq1[nt] = cvt8(wp + 32);
    }
#pragma unroll
    for (int qt = 0; qt < 2; ++qt) {
      const int qg = qbase + wave * 32 + qt * 16 + l16;
      const float* xpq = Xq + (size_t)(b * LQ + qg) * HID + h * 64 + quad * 8;
      const f16x8 bq0 = cvt8(xpq), bq1 = cvt8(xpq + 32);
#pragma unroll
      for (int nt = 0; nt < 4; ++nt) {
        f32x4 d = {0.f, 0.f, 0.f, 0.f};
        d = MFMA(wq0[nt], bq0, d);
        d = MFMA(wq1[nt], bq1, d);
        *(uint2*)&Pl[wave][qt][l16 * KP + nt * 16 + quad * 4] =
            pk4(d[0] * SC, d[1] * SC, d[2] * SC, d[3] * SC);
      }
      aq0[qt] = ld8(&Pl[wave][qt][l16 * KP + quad * 8]);
      aq1[qt] = ld8(&Pl[wave][qt][l16 * KP + 32 + quad * 8]);
    }
  }

  // ---- projection weight fragments, once per block: waves 0-3 hold Wk
  // (A-operand of K proj), waves 4-7 hold Wv (B-operand of V proj). ----
  const float* Wsel = (wave < 4) ? Wk : Wv;
  f16x8 aw0[4], aw1[4];
#pragma unroll
  for (int nt = 0; nt < 4; ++nt) {
    const float* wp = Wsel + (nt * 16 + l16) * DIM + quad * 8;
    aw0[nt] = cvt8(wp);
    aw1[nt] = cvt8(wp + 32);
  }

  const f32x4 z4 = {0.f, 0.f, 0.f, 0.f};

  // ---- proj(0) into buffer 0 (xf holds X[0]; compiler waits vmcnt here) ----
  {
    const f16x8 bx0 = pk8(xf0, xf1), bx1 = pk8(xf2, xf3);
    if (wave < 4) {
#pragma unroll
      for (int nt = 0; nt < 4; ++nt) {
        f32x4 d = z4;
        d = MFMA(aw0[nt], bx0, d);
        d = MFMA(aw1[nt], bx1, d);
        *(uint2*)&Kl[0][(kw * 16 + l16) * KP + nt * 16 + quad * 4] =
            pk4(d[0], d[1], d[2], d[3]);
      }
    } else {
#pragma unroll
      for (int dt = 0; dt < 4; ++dt) {
        f32x4 d = z4;
        d = MFMA(bx0, aw0[dt], d);
        d = MFMA(bx1, aw1[dt], d);
        *(uint2*)&Vl[0][(dt * 16 + l16) * KP + kw * 16 + quad * 4] =
            pk4(d[0], d[1], d[2], d[3]);
      }
    }
  }
  loadX(64);      // X[1] in flight across the barrier
  lds_barrier();  // publishes KV[0]; X loads NOT drained

  f32x4 o[2][4];
  float l_run[2] = {0.f, 0.f};
#pragma unroll
  for (int qt = 0; qt < 2; ++qt)
#pragma unroll
    for (int i = 0; i < 4; ++i) o[qt][i] = z4;

  for (int t = 0; t < NKT; ++t) {
    const int buf = t & 1;
    const int kt = t * 64;

    // mask loads first (vmem FIFO: older X[t+1] loads drain independently;
    // waiting on these later leaves X[t+2] in flight). L2-hot, quad-broadcast.
    float4 mq[4];
#pragma unroll
    for (int nt = 0; nt < 4; ++nt)
      mq[nt] = *(const float4*)(mg + kt + nt * 16 + quad * 4);

    // ---- proj(t+1) into buf^1 (reads nothing of buf; races nothing) ----
    if (t + 1 < NKT) {
      const f16x8 bx0 = pk8(xf0, xf1), bx1 = pk8(xf2, xf3);  // counted vmcnt wait
      if (wave < 4) {
#pragma unroll
        for (int nt = 0; nt < 4; ++nt) {
          f32x4 d = z4;
          d = MFMA(aw0[nt], bx0, d);
          d = MFMA(aw1[nt], bx1, d);
          *(uint2*)&Kl[buf ^ 1][(kw * 16 + l16) * KP + nt * 16 + quad * 4] =
              pk4(d[0], d[1], d[2], d[3]);
        }
      } else {
#pragma unroll
        for (int dt = 0; dt < 4; ++dt) {
          f32x4 d = z4;
          d = MFMA(bx0, aw0[dt], d);
          d = MFMA(bx1, aw1[dt], d);
          *(uint2*)&Vl[buf ^ 1][(dt * 16 + l16) * KP + kw * 16 + quad * 4] =
              pk4(d[0], d[1], d[2], d[3]);
        }
      }
      if (t + 2 < NKT) loadX(kt + 128);  // X[t+2]: in flight across next barrier
    }

    // additive mask in exp2 domain, as S-accumulator INIT (D-layout match:
    // C[r] = mask[key=nt*16+quad*4+r]); fma form: NEGM - m*NEGM
    f32x4 cin[4];
#pragma unroll
    for (int nt = 0; nt < 4; ++nt) {
      cin[nt][0] = __builtin_fmaf(mq[nt].x, -NEGM, NEGM);
      cin[nt][1] = __builtin_fmaf(mq[nt].y, -NEGM, NEGM);
      cin[nt][2] = __builtin_fmaf(mq[nt].z, -NEGM, NEGM);
      cin[nt][3] = __builtin_fmaf(mq[nt].w, -NEGM, NEGM);
    }

    // S^T = K.Q^T : D[key=nt*16+quad*4+r][q=l16], C-init = mask; P = exp2(S)
    float p[2][4][4];
    __builtin_amdgcn_s_setprio(1);
#pragma unroll
    for (int nt = 0; nt < 4; ++nt) {
      const f16x8 kb0 = ld8(&Kl[buf][(nt * 16 + l16) * KP + quad * 8]);
      const f16x8 kb1 = ld8(&Kl[buf][(nt * 16 + l16) * KP + 32 + quad * 8]);
#pragma unroll
      for (int qt = 0; qt < 2; ++qt) {
        f32x4 s = cin[nt];
        s = MFMA(kb0, aq0[qt], s);
        s = MFMA(kb1, aq1[qt], s);
        const float e0 = __builtin_amdgcn_exp2f(s[0]);
        const float e1 = __builtin_amdgcn_exp2f(s[1]);
        const float e2 = __builtin_amdgcn_exp2f(s[2]);
        const float e3 = __builtin_amdgcn_exp2f(s[3]);
        l_run[qt] += (e0 + e1) + (e2 + e3);
        p[qt][nt][0] = e0; p[qt][nt][1] = e1; p[qt][nt][2] = e2; p[qt][nt][3] = e3;
      }
    }
    __builtin_amdgcn_s_setprio(0);

    // P: C-layout -> A-layout, per-wave per-qt buffers; write both qt then
    // read both so the two LDS round-trip latencies overlap
#pragma unroll
    for (int qt = 0; qt < 2; ++qt)
#pragma unroll
      for (int nt = 0; nt < 4; ++nt)
        *(uint2*)&Pl[wave][qt][l16 * KP + nt * 16 + quad * 4] =
            pk4(p[qt][nt][0], p[qt][nt][1], p[qt][nt][2], p[qt][nt][3]);
    f16x8 ap0[2], ap1[2];
#pragma unroll
    for (int qt = 0; qt < 2; ++qt) {
      ap0[qt] = ld8(&Pl[wave][qt][l16 * KP + quad * 8]);
      ap1[qt] = ld8(&Pl[wave][qt][l16 * KP + 32 + quad * 8]);
    }

    // O^T += V.P^T : D[d=dt*16+quad*4+r][q=l16]
    __builtin_amdgcn_s_setprio(1);
#pragma unroll
    for (int dt = 0; dt < 4; ++dt) {
      const f16x8 vb0 = ld8(&Vl[buf][(dt * 16 + l16) * KP + quad * 8]);
      const f16x8 vb1 = ld8(&Vl[buf][(dt * 16 + l16) * KP + 32 + quad * 8]);
#pragma unroll
      for (int qt = 0; qt < 2; ++qt) {
        o[qt][dt] = MFMA(vb0, ap0[qt], o[qt][dt]);
        o[qt][dt] = MFMA(vb1, ap1[qt], o[qt][dt]);
      }
    }
    __builtin_amdgcn_s_setprio(0);

    lds_barrier();  // publishes KV[t+1]; guards buf reuse; X loads survive
  }

  // row-sum: lane covers its quad's 16 keys; finish across quads
  float inv[2];
#pragma unroll
  for (int qt = 0; qt < 2; ++qt) {
    float s = l_run[qt];
    s += __shfl_xor(s, 16);
    s += __shfl_xor(s, 32);
    inv[qt] = 1.f / s;
  }
  // ctx (token, h*64+d): lane's 4 d-values contiguous -> packed 8B stores
#pragma unroll
  for (int qt = 0; qt < 2; ++qt) {
    const int qg = qbase + wave * 32 + qt * 16 + l16;
    _Float16* base = ctx + (size_t)(b * LQ + qg) * HID + h * 64;
#pragma unroll
    for (int dt = 0; dt < 4; ++dt)
      *(uint2*)(base + dt * 16 + quad * 4) =
          pk4(o[qt][dt][0] * inv[qt], o[qt][dt][1] * inv[qt],
              o[qt][dt][2] * inv[qt], o[qt][dt][3] * inv[qt]);
  }
}

// ---------------------------------------------------------------------------
// W_lin fp32 -> fp16 (once; 2MB result stays L2-resident for linear_kernel)
// ---------------------------------------------------------------------------
__global__ __launch_bounds__(256) void wconv_kernel(const float* __restrict__ W,
                                                    _Float16* __restrict__ Wh) {
  const int i = blockIdx.x * 256 + threadIdx.x;
  const float4 v = ((const float4*)W)[i];
  ((uint2*)Wh)[i] = pk4(v.x, v.y, v.z, v.w);
}

// ---------------------------------------------------------------------------
// lin = ctx @ Wh^T + b; X = erf-GELU(lin) + resid. 128x128 tile, 512 threads
// (8 waves as 2x4), BK=64, double-buffered global_load_lds, 1 barrier/chunk.
// ---------------------------------------------------------------------------
__global__ __launch_bounds__(512) void linear_kernel(const _Float16* __restrict__ A,
                                                     const _Float16* __restrict__ Wh,
                                                     const float* __restrict__ bias,
                                                     const float* __restrict__ resid,
                                                     float* __restrict__ Xout) {
  __shared__ __align__(16) _Float16 Al[2][128 * 64];
  __shared__ __align__(16) _Float16 Bl[2][128 * 64];
  const int tid = threadIdx.x;
  const int wave = tid >> 6, lane = tid & 63, l16 = lane & 15, quad = lane >> 4;
  const int wm = wave >> 2, wn = wave & 3;
  const int nbase = blockIdx.x * 128, mbase = blockIdx.y * 128;
  const int srow = wave * 16 + (lane >> 3);
  const int sc = lane & 7;

  auto stage = [&](int kk, int nbuf) {
#pragma unroll
    for (int i = 0; i < 2; ++i) {
      const int row = srow + i * 8;
      const int c = sc ^ (row & 7);
      gl_lds16(A + (size_t)(mbase + row) * HID + kk + c * 8,
               &Al[nbuf][(wave * 16 + i * 8) * 64]);
      gl_lds16(Wh + (size_t)(nbase + row) * HID + kk + c * 8,
               &Bl[nbuf][(wave * 16 + i * 8) * 64]);
    }
  };

  const f32x4 z4 = {0.f, 0.f, 0.f, 0.f};
  f32x4 acc[4][2];
#pragma unroll
  for (int mt = 0; mt < 4; ++mt)
#pragma unroll
    for (int nt = 0; nt < 2; ++nt) acc[mt][nt] = z4;

  stage(0, 0);
  for (int t = 0; t < HID / 64; ++t) {
    const int buf = t & 1;
    __syncthreads();
    if (t + 1 < HID / 64) stage((t + 1) * 64, buf ^ 1);
    const int sw = l16 & 7;
    f16x8 b0[2], b1[2];
#pragma unroll
    for (int nt = 0; nt < 2; ++nt) {
      const int brow = wn * 32 + nt * 16 + l16;
      b0[nt] = ld8(&Bl[buf][brow * 64 + (quad ^ sw) * 8]);
      b1[nt] = ld8(&Bl[buf][brow * 64 + ((quad + 4) ^ sw) * 8]);
    }
#pragma unroll
    for (int mt = 0; mt < 4; ++mt) {
      const int arow = wm * 64 + mt * 16 + l16;
      const f16x8 a0 = ld8(&Al[buf][arow * 64 + (quad ^ sw) * 8]);
      const f16x8 a1 = ld8(&Al[buf][arow * 64 + ((quad + 4) ^ sw) * 8]);
#pragma unroll
      for (int nt = 0; nt < 2; ++nt) {
        acc[mt][nt] = MFMA(a0, b0[nt], acc[mt][nt]);
        acc[mt][nt] = MFMA(a1, b1[nt], acc[mt][nt]);
      }
    }
  }
#pragma unroll
  for (int nt = 0; nt < 2; ++nt) {
    const int col = nbase + wn * 32 + nt * 16 + l16;
    const float bv = bias[col];
#pragma unroll
    for (int mt = 0; mt < 4; ++mt) {
#pragma unroll
      for (int r = 0; r < 4; ++r) {
        const int row = mbase + wm * 64 + mt * 16 + quad * 4 + r;
        const float v = acc[mt][nt][r] + bv;
        const float g = 0.5f * v * (1.f + erff(v * 0.70710678118654752f));
        Xout[(size_t)row * HID + col] = g + resid[(size_t)row * HID + col];
      }
    }
  }
}

// ---------------------------------------------------------------------------
// LayerNorm over HID=1024 per token row.
// ---------------------------------------------------------------------------
__global__ __launch_bounds__(256) void ln_kernel(const float* __restrict__ X,
                                                 const float* __restrict__ gamma,
                                                 const float* __restrict__ beta,
                                                 float* __restrict__ out) {
  const int row = blockIdx.x, tid = threadIdx.x;
  const int lane = tid & 63, wave = tid >> 6;
  const float4 v = *(const float4*)(X + (size_t)row * HID + tid * 4);
  float s1 = v.x + v.y + v.z + v.w;
  float s2 = v.x * v.x + v.y * v.y + v.z * v.z + v.w * v.w;
#pragma unroll
  for (int off = 1; off < 64; off <<= 1) {
    s1 += __shfl_xor(s1, off);
    s2 += __shfl_xor(s2, off);
  }
  __shared__ float r1[4], r2[4];
  if (lane == 0) { r1[wave] = s1; r2[wave] = s2; }
  __syncthreads();
  s1 = r1[0] + r1[1] + r1[2] + r1[3];
  s2 = r2[0] + r2[1] + r2[2] + r2[3];
  const float mu = s1 * (1.f / HID);
  const float var = s2 * (1.f / HID) - mu * mu;
  const float rstd = rsqrtf(var + 1e-5f);
  const float4 g = *(const float4*)(gamma + tid * 4);
  const float4 be = *(const float4*)(beta + tid * 4);
  float4 ov;
  ov.x = (v.x - mu) * rstd * g.x + be.x;
  ov.y = (v.y - mu) * rstd * g.y + be.y;
  ov.z = (v.z - mu) * rstd * g.z + be.z;
  ov.w = (v.w - mu) * rstd * g.w + be.w;
  *(float4*)(out + (size_t)row * HID + tid * 4) = ov;
}

// ---------------------------------------------------------------------------
// Workspace:
//   ctx fp16 [ 0, 8M)
//   Xb  fp32 [ 8M,24M)
//   Wh  fp16 [24M,26M)
// ---------------------------------------------------------------------------
extern "C" void kernel_launch(void* const* d_in, const int* in_sizes, int n_in,
                              void* d_out, int out_size, void* d_ws, size_t ws_size,
                              hipStream_t stream) {
  (void)in_sizes; (void)n_in; (void)out_size; (void)ws_size;
  const float* input_embed = (const float*)d_in[0];
  const float* kg_embed    = (const float*)d_in[1];
  // d_in[2] = input_mask: additive per-query constant -> softmax-invariant, unused
  const float* kg_mask = (const float*)d_in[3];
  const float* Wq    = (const float*)d_in[4];
  const float* Wk    = (const float*)d_in[5];
  const float* Wv    = (const float*)d_in[6];
  const float* W_lin = (const float*)d_in[7];
  const float* b_lin = (const float*)d_in[8];
  const float* gamma = (const float*)d_in[9];
  const float* beta  = (const float*)d_in[10];

  char* ws = (char*)d_ws;
  _Float16* ctx = (_Float16*)(ws);
  float*    Xb  = (float*)(ws + (8u << 20));
  _Float16* Wh  = (_Float16*)(ws + (24u << 20));

  attn_kernel<<<dim3(128, 2), dim3(512), 0, stream>>>(input_embed, kg_embed, Wq, Wk, Wv,
                                                      kg_mask, ctx);
  wconv_kernel<<<dim3(1024), dim3(256), 0, stream>>>(W_lin, Wh);
  linear_kernel<<<dim3(8, 32), dim3(512), 0, stream>>>(ctx, Wh, b_lin, input_embed, Xb);
  ln_kernel<<<dim3(NTOK), dim3(256), 0, stream>>>(Xb, gamma, beta, (float*)d_out);
}